// Round 2
// baseline (365.376 us; speedup 1.0000x reference)
//
#include <hip/hip_runtime.h>

// Problem constants (from reference)
#define VOCAB 32000
#define D     64
#define B     32
#define S     512
#define NCHUNK 8     // number of time chunks
#define CLEN   64    // chunk length (S / NCHUNK)

typedef float vf4 __attribute__((ext_vector_type(4)));

// ---------------------------------------------------------------------------
// Single fused kernel.
// Grid: B * NCHUNK * 4 = 1024 blocks (c fastest-varying for CU load balance),
// 256 threads = 16 i-rows x 16 jq (float4 over j).
//
// Each block owns (b, chunk c, iBase): it redundantly pre-scans
// t = 0 .. c*CLEN-1 (no stores; emb rows are L1/L2-resident broadcasts),
// then replays its 64-step chunk writing every state with nontemporal
// float4 stores (268 MB > L3, pure stream -> skip write-allocate).
//
// All 1024 blocks are co-resident (4 blocks/CU, 16 waves/CU), so the
// pre-scan of high-c blocks overlaps the store traffic of low-c blocks.
// Recurrence op order matches the reference scan exactly (fma(ci*cj, rho*d)).
// ---------------------------------------------------------------------------
__global__ __launch_bounds__(256, 4) void qmn_fused(
    const int*  __restrict__ x,      // [B, S]
    const float* __restrict__ emb,   // [VOCAB, D]
    vf4*        __restrict__ out4)   // [B, S, D, D] as float4 over last dim
{
    const float DECAY = 0.9f;

    int blk   = blockIdx.x;
    int c     = blk & (NCHUNK - 1);          // fastest-varying: balance CUs
    int iBase = ((blk >> 3) & 3) * 16;
    int b     = blk >> 5;

    int jq = threadIdx.x & 15;               // float4 index over j
    int i  = iBase + (threadIdx.x >> 4);     // row

    const int* xb = x + b * S;
    const vf4* embv = (const vf4*)emb;       // [VOCAB, D/4]

    // identity init
    vf4 rho;
    int j0 = jq * 4;
    rho.x = (i == j0 + 0) ? 1.0f : 0.0f;
    rho.y = (i == j0 + 1) ? 1.0f : 0.0f;
    rho.z = (i == j0 + 2) ? 1.0f : 0.0f;
    rho.w = (i == j0 + 3) ? 1.0f : 0.0f;

    const int tStart = c * CLEN;

    // ---- pre-scan: advance rho to the chunk boundary (no stores) ----
    #pragma unroll 8
    for (int t = 0; t < tStart; ++t) {
        int tok = xb[t];                     // block-uniform -> scalar load
        float ci = emb[tok * D + i];         // 4 distinct lines/wave, broadcast
        vf4  cj  = embv[tok * (D / 4) + jq]; // 256B row, L1-served
        rho.x = rho.x * DECAY + ci * cj.x;
        rho.y = rho.y * DECAY + ci * cj.y;
        rho.z = rho.z * DECAY + ci * cj.z;
        rho.w = rho.w * DECAY + ci * cj.w;
    }

    // ---- main chunk: 64 steps, store every state ----
    // out[((b*S + t)*D + i)*D + j]; wave writes 1KiB contiguous per step.
    vf4* outp = out4 + (((size_t)(b * S + tStart)) * D + i) * (D / 4) + jq;

    #pragma unroll 4
    for (int tt = 0; tt < CLEN; ++tt) {
        int tok = xb[tStart + tt];
        float ci = emb[tok * D + i];
        vf4  cj  = embv[tok * (D / 4) + jq];
        rho.x = rho.x * DECAY + ci * cj.x;
        rho.y = rho.y * DECAY + ci * cj.y;
        rho.z = rho.z * DECAY + ci * cj.z;
        rho.w = rho.w * DECAY + ci * cj.w;
        __builtin_nontemporal_store(rho, outp);
        outp += D * (D / 4);                 // advance one t: 16 KiB
    }
}

// ---------------------------------------------------------------------------
// Launch
// ---------------------------------------------------------------------------
extern "C" void kernel_launch(void* const* d_in, const int* in_sizes, int n_in,
                              void* d_out, int out_size, void* d_ws, size_t ws_size,
                              hipStream_t stream) {
    const int*   x   = (const int*)d_in[0];     // [B, S] token ids
    const float* emb = (const float*)d_in[1];   // [VOCAB, D]
    vf4* out = (vf4*)d_out;                     // [B, S, D, D]

    qmn_fused<<<B * NCHUNK * 4, 256, 0, stream>>>(x, emb, out);
}

// Round 3
// 293.994 us; speedup vs baseline: 1.2428x; 1.2428x over previous
//
#include <hip/hip_runtime.h>

// Problem constants (from reference)
#define VOCAB 32000
#define D     64
#define B     32
#define S     512
#define NCHUNK 8     // number of time chunks
#define CLEN   64    // chunk length (S / NCHUNK)

typedef float vf4 __attribute__((ext_vector_type(4)));

// ---------------------------------------------------------------------------
// Pass 1: gather content[b,s,:] = emb[x[b,s],:]   (float4 vectorized)
// 1024 blocks x 256 threads. ~8 MB of traffic, ~3 us.
// Staging makes every scan-pass read LINEAR (prefetch-friendly, L2-resident)
// instead of a token-dependent 2-level gather in the hot loops.
// ---------------------------------------------------------------------------
__global__ void qmn_gather(const int* __restrict__ x,
                           const vf4* __restrict__ emb4,
                           vf4* __restrict__ content4) {
    int tid = blockIdx.x * blockDim.x + threadIdx.x;   // [0, B*S*16)
    int bs  = tid >> 4;
    int d4  = tid & 15;
    int tok = x[bs];
    content4[tid] = emb4[tok * (D / 4) + d4];
}

// ---------------------------------------------------------------------------
// Pass 2 (fused scan+store): each block owns (b, chunk c, iBase).
// It redundantly pre-scans t = 0 .. c*CLEN-1 from linear content (no stores),
// then writes its 64 states with plain coalesced float4 stores.
//
// Block swizzle: CUs receive blocks {n, n+256, n+512, n+768}.
//   c     = blk >> 7        -> a CU's blocks span {c, c+2, c+4, c+6}: balanced
//                              pre-scan work AND stores flowing from t~0 on
//                              every CU (round-2's c = blk&7 aliased all four
//                              resident blocks to ONE c: 256 % 8 == 0).
//   b     = (blk >> 2) & 31 -> same b for all blocks on a CU (L1 locality).
//   iBase = (blk & 3) * 16
// 256 threads = 16 i-rows x 16 jq; a wave stores 1 KiB contiguous per step.
// ---------------------------------------------------------------------------
__global__ __launch_bounds__(256, 4) void qmn_chunks(
    const float* __restrict__ content,   // [B, S, D]
    vf4*        __restrict__ out4)       // [B, S, D, D] as float4 over j
{
    const float DECAY = 0.9f;

    int blk   = blockIdx.x;
    int c     = blk >> 7;
    int b     = (blk >> 2) & 31;
    int iBase = (blk & 3) * 16;

    int jq = threadIdx.x & 15;
    int i  = iBase + (threadIdx.x >> 4);

    // identity init
    vf4 rho;
    int j0 = jq * 4;
    rho.x = (i == j0 + 0) ? 1.0f : 0.0f;
    rho.y = (i == j0 + 1) ? 1.0f : 0.0f;
    rho.z = (i == j0 + 2) ? 1.0f : 0.0f;
    rho.w = (i == j0 + 3) ? 1.0f : 0.0f;

    const float* cb  = content + (size_t)b * S * D;
    const vf4*   cb4 = (const vf4*)cb;
    const int tStart = c * CLEN;

    // ---- pre-scan to the chunk boundary: linear reads, no stores ----
    // Loads are independent of the rho chain -> unrolled batches pipeline;
    // the serial dependence is 4 independent FMAs/step (~4 cyc/step).
    #pragma unroll 8
    for (int t = 0; t < tStart; ++t) {
        float ci = cb[t * D + i];            // 4 lines/wave, broadcast
        vf4   cj = cb4[t * (D / 4) + jq];    // contiguous 256B row
        rho.x = rho.x * DECAY + ci * cj.x;
        rho.y = rho.y * DECAY + ci * cj.y;
        rho.z = rho.z * DECAY + ci * cj.z;
        rho.w = rho.w * DECAY + ci * cj.w;
    }

    // ---- main chunk: 64 steps, store every state (plain stores) ----
    vf4* outp = out4 + (((size_t)(b * S + tStart)) * D + i) * (D / 4) + jq;

    #pragma unroll 4
    for (int tt = 0; tt < CLEN; ++tt) {
        int t = tStart + tt;
        float ci = cb[t * D + i];
        vf4   cj = cb4[t * (D / 4) + jq];
        rho.x = rho.x * DECAY + ci * cj.x;
        rho.y = rho.y * DECAY + ci * cj.y;
        rho.z = rho.z * DECAY + ci * cj.z;
        rho.w = rho.w * DECAY + ci * cj.w;
        *outp = rho;
        outp += D * (D / 4);                 // next t: +16 KiB
    }
}

// ---------------------------------------------------------------------------
// Launch
// ---------------------------------------------------------------------------
extern "C" void kernel_launch(void* const* d_in, const int* in_sizes, int n_in,
                              void* d_out, int out_size, void* d_ws, size_t ws_size,
                              hipStream_t stream) {
    const int*   x   = (const int*)d_in[0];     // [B, S] token ids
    const float* emb = (const float*)d_in[1];   // [VOCAB, D]
    vf4* out = (vf4*)d_out;                     // [B, S, D, D]

    float* content = (float*)d_ws;              // B*S*D floats = 4 MiB

    qmn_gather<<<B * S * (D / 4) / 256, 256, 0, stream>>>(
        x, (const vf4*)emb, (vf4*)content);

    qmn_chunks<<<B * NCHUNK * 4, 256, 0, stream>>>(content, out);
}